// Round 1
// 191.156 us; speedup vs baseline: 1.1041x; 1.1041x over previous
//
#include <hip/hip_runtime.h>

namespace {

typedef float v4f __attribute__((ext_vector_type(4)));
typedef _Float16 half4 __attribute__((ext_vector_type(4)));
typedef unsigned int uint32;

constexpr int   kB     = 32768;
constexpr int   kT     = 50;
constexpr float kDT    = 0.01f;
constexpr float kGamma = 0.1f;
constexpr float kSigma = 0.2f;
constexpr float kTau   = 0.5f;
constexpr float kA     = 2.8853900817779268f;   // 2*log2(e)

// 17 MFMA A-fragment images for v_mfma_f32_16x16x16_f16:
// lane holds A[m][k], m = lane&15, k = (lane>>4)*4 + j  (2 dwords f16 / lane).
// ACTIVATION-FOLDED as before: act(v) = rcp(exp2(v)+1); tanh = 1-2r absorbed
// into next layer (W' = -2W, bias' = b + sumW); act-feeding layers pre-scaled
// by kA. Biases/t-rows live in a float section consumed as MFMA C-initializers
// (C/D row mapping == B k mapping for the K=16 shape -> no shuffles needed).
//
// Fragments: 0 y0L1  1 y0L2  2 y0L3  3 L1z(x)  4 L1p(x)  5 L2z  6 L2p
//            7 L3z  8 L3p  9 A-row  10 B-row  11 C-row  12 D-row
//            13 A-col 14 C-col 15 B-col 16 D-col
constexpr int kNFrag      = 17;
constexpr int kFragDwords = kNFrag * 128;
constexpr int kBiasFloats = 11 * 16;
// bias arrays (16 floats each):
// 0 y0c1  1 y0c2  2 y0c3  3 c2z  4 c2p  5 c3z  6 c3p
// 7 vtz(t-row z)  8 vbz  9 vtp  10 vbp

__device__ __forceinline__ float fact(float x) {   // rcp(exp2(x)+1)
  return __builtin_amdgcn_rcpf(exp2f(x) + 1.0f);
}

__device__ __forceinline__ uint32 pk2(float a, float b) {
  union { _Float16 h[2]; uint32 u; } z;
  z.h[0] = (_Float16)a; z.h[1] = (_Float16)b;
  return z.u;
}

__device__ __forceinline__ v4f act4(v4f a) {
  v4f r;
  r[0] = fact(a[0]); r[1] = fact(a[1]);
  r[2] = fact(a[2]); r[3] = fact(a[3]);
  return r;
}

// ---------------- prep: build folded A-fragment images (f16) ----------------
__global__ __launch_bounds__(256) void prep_kernel(
    const float* __restrict__ A,   const float* __restrict__ Bm,
    const float* __restrict__ Cm,  const float* __restrict__ Dm,
    const float* __restrict__ pW1, const float* __restrict__ pb1,
    const float* __restrict__ pW2, const float* __restrict__ pb2,
    const float* __restrict__ pW3, const float* __restrict__ pb3,
    const float* __restrict__ zW1, const float* __restrict__ zb1,
    const float* __restrict__ zW2, const float* __restrict__ zb2,
    const float* __restrict__ zW3, const float* __restrict__ zb3,
    const float* __restrict__ yW1, const float* __restrict__ yb1,
    const float* __restrict__ yW2, const float* __restrict__ yb2,
    const float* __restrict__ yW3, const float* __restrict__ yb3,
    uint32* __restrict__ ws, float* __restrict__ out)
{
  const int tid = threadIdx.x;
  if (tid < 2) out[tid] = 0.0f;

  auto sum10 = [](const float* W, int stride, int m) {
    float s = 0.f;
    for (int j = 0; j < 10; ++j) s += W[j * stride + m];
    return s;
  };

  // k in [0,16)
  auto wval = [&](int p, int m, int k) -> float {
    switch (p) {
      case 0:  return (m < 10) ? kA * yW1[k * 10 + m] : 0.f;
      case 1:  return (m < 10 && k < 10) ? -2.f * kA * yW2[k * 10 + m] : 0.f;
      case 2:  return (k < 10) ? -2.f * yW3[k * 16 + m] : 0.f;
      case 3:  return (m < 10) ? kA * zW1[(k + 1) * 10 + m] : 0.f;
      case 4:  return (m < 10) ? kA * pW1[(k + 1) * 10 + m] : 0.f;
      case 5:  return (m < 10 && k < 10) ? -2.f * kA * zW2[k * 10 + m] : 0.f;
      case 6:  return (m < 10 && k < 10) ? -2.f * kA * pW2[k * 10 + m] : 0.f;
      case 7:  return (k < 10) ? -2.f * zW3[k * 16 + m] : 0.f;
      case 8:  return (m < 8 && k < 10) ? -2.f * pW3[k * 8 + m] : 0.f;
      case 9:  return A[m * 16 + k];                      // dx: x @ A^T
      case 10: return (k < 8) ? Bm[m * 8 + k] : 0.f;      // dx: u @ B^T
      case 11: return Cm[m * 16 + k];                     // fx: x @ C^T
      case 12: return (k < 8) ? Dm[m * 8 + k] : 0.f;      // fx: u @ D^T
      case 13: return A[k * 16 + m];                      // dy: Y @ A
      case 14: return Cm[k * 16 + m];                     // dy: Z @ C
      case 15: return (m < 8) ? Bm[k * 8 + m] : 0.f;      // dh: Y @ B
      case 16: return (m < 8) ? Dm[k * 8 + m] : 0.f;      // dh: Z @ D
    }
    return 0.f;
  };

  for (int idx = tid; idx < kFragDwords; idx += 256) {
    int p = idx >> 7, r = idx & 127;
    int lane = r >> 1, dwi = r & 1;
    int m = lane & 15, q = lane >> 4;
    int k0 = 4 * q + 2 * dwi;
    ws[idx] = pk2(wval(p, m, k0), wval(p, m, k0 + 1));
  }

  float* bsf = (float*)(ws + kFragDwords);
  auto bval = [&](int a, int m) -> float {
    switch (a) {
      case 0:  return (m < 10) ? kA * yb1[m] : 0.f;
      case 1:  return (m < 10) ? kA * (yb2[m] + sum10(yW2, 10, m)) : 0.f;
      case 2:  return yb3[m] + sum10(yW3, 16, m);
      case 3:  return (m < 10) ? kA * (zb2[m] + sum10(zW2, 10, m)) : 0.f;
      case 4:  return (m < 10) ? kA * (pb2[m] + sum10(pW2, 10, m)) : 0.f;
      case 5:  return zb3[m] + sum10(zW3, 16, m);
      case 6:  return (m < 8) ? pb3[m] + sum10(pW3, 8, m) : 0.f;
      case 7:  return (m < 10) ? kA * zW1[m] : 0.f;   // zW1 row 0 = t-row
      case 8:  return (m < 10) ? kA * zb1[m] : 0.f;
      case 9:  return (m < 10) ? kA * pW1[m] : 0.f;
      case 10: return (m < 10) ? kA * pb1[m] : 0.f;
    }
    return 0.f;
  };
  for (int j = tid; j < kBiasFloats; j += 256) {
    bsf[j] = bval(j >> 4, j & 15);
  }
}

// ---------------- main: K=16 MFMA chain, zero cross-lane in time loop -------
__global__ __launch_bounds__(64)
__attribute__((amdgpu_waves_per_eu(2, 2)))
void bsde_kernel(const float* __restrict__ dw, const float* __restrict__ X0,
                 const uint32* __restrict__ wsu, float* __restrict__ out)
{
  const int lane = threadIdx.x;
  const int col  = lane & 15;
  const int quad = lane >> 4;
  const int e    = blockIdx.x * 16 + col;
  const int bq   = quad * 4;

  half4 af[kNFrag];
#pragma unroll
  for (int p = 0; p < kNFrag; ++p) {
    union { uint2 u; half4 h; } z;
    z.u = *(const uint2*)(wsu + p * 128 + lane * 2);
    af[p] = z.h;
  }

  const float* bsf = (const float*)(wsu + kFragDwords);
  const v4f c2z = *(const v4f*)&bsf[3 * 16 + bq];
  const v4f c2p = *(const v4f*)&bsf[4 * 16 + bq];
  const v4f c3z = *(const v4f*)&bsf[5 * 16 + bq];
  const v4f c3p = *(const v4f*)&bsf[6 * 16 + bq];
  const v4f vtz = *(const v4f*)&bsf[7 * 16 + bq];
  const v4f vbz = *(const v4f*)&bsf[8 * 16 + bq];
  const v4f vtp = *(const v4f*)&bsf[9 * 16 + bq];
  const v4f vbp = *(const v4f*)&bsf[10 * 16 + bq];

  auto pk4 = [](v4f a) -> half4 {
    half4 h;
    h[0] = (_Float16)a[0]; h[1] = (_Float16)a[1];
    h[2] = (_Float16)a[2]; h[3] = (_Float16)a[3];
    return h;
  };
  auto mm = [](half4 a, half4 b, v4f c) -> v4f {
    return __builtin_amdgcn_mfma_f32_16x16x16f16(a, b, c, 0, 0, 0);
  };

  const v4f zero4 = {0.f, 0.f, 0.f, 0.f};
  const v4f gam4  = {kGamma, kGamma, kGamma, kGamma};
  const v4f sig4  = {kSigma, kSigma, kSigma, kSigma};

  // ---- X0 + Y0 MLP ----
  v4f x4 = *(const v4f*)&X0[e * 16 + bq];   // C-layout rows 4q..4q+3
  half4 xB = pk4(x4);
  v4f y4;
  {
    v4f cy1 = *(const v4f*)&bsf[0 * 16 + bq];
    v4f cy2 = *(const v4f*)&bsf[1 * 16 + bq];
    v4f cy3 = *(const v4f*)&bsf[2 * 16 + bq];
    v4f h = mm(af[0], xB, cy1);
    v4f g = mm(af[1], pk4(act4(h)), cy2);
    y4    = mm(af[2], pk4(act4(g)), cy3);
  }

  float lcp = 0.0f;
  float dwv = dw[e];

  // ------------------------------- time loop -------------------------------
#pragma unroll 1
  for (int t = 0; t < kT; ++t) {
    float dwn = (t < kT - 1) ? dw[(t + 1) * kB + e] : 0.0f;
    const float tv = (float)t * kDT;
    const float wt = (t == 0 || t == kT - 1) ? 1.0f : 2.0f;

    half4 yB = pk4(y4);

    // x/y-only parts of the drift MFMAs issue first; latency hides under MLPs
    v4f dx1 = mm(af[9],  xB, gam4);
    v4f fx1 = mm(af[11], xB, sig4);
    v4f dy1 = mm(af[13], yB, zero4);
    v4f dh1 = mm(af[15], yB, zero4);

    // L1 C-init carries the t-row and bias: c = kA*(t*W_t + b)
    v4f c1z, c1p;
#pragma unroll
    for (int r = 0; r < 4; ++r) {
      c1z[r] = vbz[r] + tv * vtz[r];
      c1p[r] = vbp[r] + tv * vtp[r];
    }

    v4f hz = mm(af[3], xB, c1z);
    v4f hp = mm(af[4], xB, c1p);
    v4f gz = mm(af[5], pk4(act4(hz)), c2z);
    v4f gp = mm(af[6], pk4(act4(hp)), c2p);
    v4f zv = mm(af[7], pk4(act4(gz)), c3z);
    v4f uu = mm(af[8], pk4(act4(gp)), c3p);   // rows >= 8 are exactly 0

    half4 zB = pk4(zv);
    half4 uB = pk4(uu);
    v4f dx = mm(af[10], uB, dx1);   // x@A^T + u@B^T + gamma
    v4f fx = mm(af[12], uB, fx1);   // x@C^T + u@D^T + sigma
    v4f dy = mm(af[14], zB, dy1);   // Y@A + Z@C
    v4f dh = mm(af[16], zB, dh1);   // Y@B + Z@D (rows >= 8 zero)

    float ss = 0.0f;
    v4f Xn, Yn;
#pragma unroll
    for (int r = 0; r < 4; ++r) {
      Xn[r] = x4[r] + kDT * dx[r] + dwv * fx[r];
      Yn[r] = y4[r] - kDT * (dy[r] + x4[r]) + dwv * zv[r];
      float d = dh[r] + uu[r];            // rows>=8: both 0
      ss += d * d;
    }
    lcp += (0.5f * kDT * kTau * kTau) * wt * ss;
    x4 = Xn; y4 = Yn;
    xB = pk4(x4);
    dwv = dwn;
  }

  // ---- losses ----
  float bp = 0.0f;
#pragma unroll
  for (int r = 0; r < 4; ++r) { float d = y4[r] - x4[r]; bp += d * d; }

#pragma unroll
  for (int s = 32; s > 0; s >>= 1) {
    bp  += __shfl_down(bp,  s, 64);
    lcp += __shfl_down(lcp, s, 64);
  }
  if (lane == 0) {
    atomicAdd(&out[0], bp  * (1.0f / (float)kB));
    atomicAdd(&out[1], lcp * (1.0f / (float)kB));
  }
}

} // namespace

extern "C" void kernel_launch(void* const* d_in, const int* in_sizes, int n_in,
                              void* d_out, int out_size, void* d_ws, size_t ws_size,
                              hipStream_t stream) {
  (void)in_sizes; (void)n_in; (void)ws_size; (void)out_size;

  const float* dw  = (const float*)d_in[0];
  const float* X0  = (const float*)d_in[1];
  const float* A   = (const float*)d_in[2];
  const float* Bm  = (const float*)d_in[3];
  const float* Cm  = (const float*)d_in[4];
  const float* Dm  = (const float*)d_in[5];
  const float* pW1 = (const float*)d_in[6];
  const float* pb1 = (const float*)d_in[7];
  const float* pW2 = (const float*)d_in[8];
  const float* pb2 = (const float*)d_in[9];
  const float* pW3 = (const float*)d_in[10];
  const float* pb3 = (const float*)d_in[11];
  const float* zW1 = (const float*)d_in[12];
  const float* zb1 = (const float*)d_in[13];
  const float* zW2 = (const float*)d_in[14];
  const float* zb2 = (const float*)d_in[15];
  const float* zW3 = (const float*)d_in[16];
  const float* zb3 = (const float*)d_in[17];
  const float* yW1 = (const float*)d_in[18];
  const float* yb1 = (const float*)d_in[19];
  const float* yW2 = (const float*)d_in[20];
  const float* yb2 = (const float*)d_in[21];
  const float* yW3 = (const float*)d_in[22];
  const float* yb3 = (const float*)d_in[23];
  float* out = (float*)d_out;
  unsigned int* ws = (unsigned int*)d_ws;

  prep_kernel<<<1, 256, 0, stream>>>(
      A, Bm, Cm, Dm,
      pW1, pb1, pW2, pb2, pW3, pb3,
      zW1, zb1, zW2, zb2, zW3, zb3,
      yW1, yb1, yW2, yb2, yW3, yb3, ws, out);

  bsde_kernel<<<kB / 16, 64, 0, stream>>>(dw, X0, ws, out);
}